// Round 5
// baseline (802.670 us; speedup 1.0000x reference)
//
#include <hip/hip_runtime.h>

#define IN_F 128
#define OUT_F 128
#define BROWS 64        // destination rows per bucket
#define BCAP  2048      // slab capacity per bucket; E[edges/bucket]=1024 (Poisson) -> P(overflow)~0
#define NBMAX 1024      // LDS histogram size (>= n_buckets = 782)

typedef __attribute__((ext_vector_type(8))) short short8;   // 8 bf16 = 4 VGPRs
typedef __attribute__((ext_vector_type(4))) float floatx4;  // MFMA C/D

// fp32 -> bf16 (RNE) as raw short
__device__ __forceinline__ short f2bf(float f) {
  union { float f; unsigned u; } v; v.f = f;
  unsigned u = v.u;
  unsigned r = (u + 0x7fffu + ((u >> 16) & 1u)) >> 16;
  return (short)r;
}
__device__ __forceinline__ float bflo(unsigned u) { return __uint_as_float(u << 16); }
__device__ __forceinline__ float bfhi(unsigned u) { return __uint_as_float(u & 0xffff0000u); }

// ---------------------------------------------------------------------------
// Prep: wt[n][k] = bf16(W[k][n])
// ---------------------------------------------------------------------------
__global__ __launch_bounds__(256) void prep_wt(const float* __restrict__ w,
                                               short* __restrict__ wt) {
  int i = blockIdx.x * 256 + threadIdx.x;   // i = n*128 + k
  int n = i >> 7, k = i & 127;
  wt[i] = f2bf(w[k * 128 + n]);
}

// ---------------------------------------------------------------------------
// GEMM: sup(bf16) = X(fp32->bf16) @ W via mfma_f32_16x16x32_bf16. (unchanged)
// ---------------------------------------------------------------------------
__global__ __launch_bounds__(256) void gemm_mfma(const float* __restrict__ x,
                                                 const short* __restrict__ wt,
                                                 unsigned short* __restrict__ sup,
                                                 int n) {
  const int w    = threadIdx.x >> 6;
  const int lane = threadIdx.x & 63;
  const int m    = lane & 15;
  const int q    = lane >> 4;
  const int row  = blockIdx.x * 64 + w * 16 + m;

  floatx4 acc[8];
#pragma unroll
  for (int t = 0; t < 8; ++t) acc[t] = (floatx4)(0.f);

#pragma unroll
  for (int kk = 0; kk < 4; ++kk) {
    short8 a;
    if (row < n) {
      const float4* px = (const float4*)(x + (size_t)row * IN_F + kk * 32 + q * 8);
      float4 lo = px[0], hi = px[1];
      a[0] = f2bf(lo.x); a[1] = f2bf(lo.y); a[2] = f2bf(lo.z); a[3] = f2bf(lo.w);
      a[4] = f2bf(hi.x); a[5] = f2bf(hi.y); a[6] = f2bf(hi.z); a[7] = f2bf(hi.w);
    } else {
      a = (short8)(0);
    }
#pragma unroll
    for (int t = 0; t < 8; ++t) {
      short8 b = *(const short8*)(wt + (size_t)(16 * t + m) * 128 + kk * 32 + q * 8);
      acc[t] = __builtin_amdgcn_mfma_f32_16x16x32_bf16(a, b, acc[t], 0, 0, 0);
    }
  }

#pragma unroll
  for (int r = 0; r < 4; ++r) {
    int row_out = blockIdx.x * 64 + w * 16 + q * 4 + r;
    if (row_out < n) {
#pragma unroll
      for (int t = 0; t < 8; ++t) {
        sup[(size_t)row_out * OUT_F + 16 * t + m] = (unsigned short)f2bf(acc[t][r]);
      }
    }
  }
}

// ---------------------------------------------------------------------------
// cursor[b] = b * BCAP  (slab write cursors; d_ws is re-poisoned every launch)
// ---------------------------------------------------------------------------
__global__ __launch_bounds__(256) void init_cursor(int* __restrict__ cursor, int nb) {
  int b = blockIdx.x * 256 + threadIdx.x;
  if (b < nb) cursor[b] = b * BCAP;
}

// ---------------------------------------------------------------------------
// Bin edges into 64-row buckets. Per block: LDS histogram (rank via LDS
// atomic), ONE global atomic per (block,bucket) to reserve slab space, then
// bucket-grouped writes (runs of ~5 records -> low write amplification).
// Record: word0 = col | (row_local<<16), word1 = val bits.
// ---------------------------------------------------------------------------
__global__ __launch_bounds__(256) void bin_edges(const int* __restrict__ erow,
                                                 const int* __restrict__ ecol,
                                                 const float* __restrict__ eval_,
                                                 int* __restrict__ cursor,
                                                 int2* __restrict__ slab,
                                                 int n_edges, int nb) {
  __shared__ int lhist[NBMAX];
  const int t = threadIdx.x;
  for (int b = t; b < nb; b += 256) lhist[b] = 0;
  __syncthreads();

  const int base = blockIdx.x * 4096;
  int meta[16], col[16]; float val[16];
#pragma unroll
  for (int i = 0; i < 16; ++i) {
    int e = base + i * 256 + t;
    meta[i] = -1;
    if (e < n_edges) {
      int r  = erow[e];
      col[i] = ecol[e];
      val[i] = eval_[e];
      int b = r >> 6, rl = r & 63;
      int rank = atomicAdd(&lhist[b], 1);            // rank within (block,bucket)
      meta[i] = (b << 18) | (rl << 12) | rank;       // 10b | 6b | 12b
    }
  }
  __syncthreads();

  for (int b = t; b < nb; b += 256) {
    int c = lhist[b];
    lhist[b] = c ? atomicAdd(&cursor[b], c) : 0;     // reserve; overwrite with base
  }
  __syncthreads();

#pragma unroll
  for (int i = 0; i < 16; ++i) {
    if (meta[i] >= 0) {
      int b = meta[i] >> 18, rl = (meta[i] >> 12) & 63, rank = meta[i] & 0xfff;
      int pos = lhist[b] + rank;
      if (pos < (b + 1) * BCAP)                      // slab overflow guard (never fires)
        slab[pos] = make_int2(col[i] | (rl << 16), __float_as_int(val[i]));
    }
  }
}

// ---------------------------------------------------------------------------
// SpMM: one block per bucket. 32 KB LDS fp32 accumulator [64 rows][128 f].
// Per edge: 64 lanes gather one dword (2 bf16) of sup[col], multiply by val,
// ds_add_f32 into LDS (fire-and-forget -> independent chains). 8 edges in
// flight per wave + record prefetch for MLP. Epilogue: +bias, coalesced write.
// ---------------------------------------------------------------------------
__global__ __launch_bounds__(256) void spmm_bucket(const int* __restrict__ cursor,
                                                   const int2* __restrict__ slab,
                                                   const unsigned* __restrict__ sup32,
                                                   const float* __restrict__ bias,
                                                   float* __restrict__ out,
                                                   int n_nodes) {
  __shared__ float acc[BROWS * OUT_F];               // 32 KB
  const int t = threadIdx.x;
  const int b = blockIdx.x;
  for (int i = t; i < BROWS * OUT_F / 4; i += 256)
    ((float4*)acc)[i] = make_float4(0.f, 0.f, 0.f, 0.f);
  __syncthreads();

  const int start = b * BCAP;
  const int cnt   = cursor[b] - start;               // edges in this bucket
  const int w = t >> 6, lane = t & 63;
  const int last = start + max(cnt - 1, 0);

  // 2-stage pipeline, 8 edges/group/wave, 4 waves -> stride 32
  int2 rec[8], nrec[8];
  int jg = w * 8;
#pragma unroll
  for (int k = 0; k < 8; ++k) rec[k] = slab[min(start + jg + k, last)];

  for (; jg < cnt; jg += 32) {
#pragma unroll
    for (int k = 0; k < 8; ++k)                      // prefetch next group
      nrec[k] = slab[min(start + jg + 32 + k, last)];
    unsigned d[8];
#pragma unroll
    for (int k = 0; k < 8; ++k)                      // 8 independent gathers
      d[k] = sup32[((size_t)(rec[k].x & 0xffff) << 6) + lane];
#pragma unroll
    for (int k = 0; k < 8; ++k) {
      float v = (jg + k < cnt) ? __int_as_float(rec[k].y) : 0.f;
      int idx = (rec[k].x >> 16) * OUT_F + lane * 2;
      atomicAdd(&acc[idx],     v * bflo(d[k]));
      atomicAdd(&acc[idx + 1], v * bfhi(d[k]));
    }
#pragma unroll
    for (int k = 0; k < 8; ++k) rec[k] = nrec[k];
  }
  __syncthreads();

  const int row0 = b * BROWS;
  for (int i = t; i < BROWS * OUT_F / 4; i += 256) {
    int row = row0 + (i >> 5);                       // 32 float4 per row
    if (row < n_nodes) {
      float4 a  = ((const float4*)acc)[i];
      float4 bb = ((const float4*)bias)[i & 31];
      ((float4*)out)[(size_t)row * 32 + (i & 31)] =
          make_float4(a.x + bb.x, a.y + bb.y, a.z + bb.z, a.w + bb.w);
    }
  }
}

extern "C" void kernel_launch(void* const* d_in, const int* in_sizes, int n_in,
                              void* d_out, int out_size, void* d_ws, size_t ws_size,
                              hipStream_t stream) {
  const float* x     = (const float*)d_in[0];
  const int*   erow  = (const int*)d_in[1];
  const int*   ecol  = (const int*)d_in[2];
  const float* eval_ = (const float*)d_in[3];
  const float* w     = (const float*)d_in[4];
  const float* bias  = (const float*)d_in[5];
  float* out = (float*)d_out;

  const int n_nodes = in_sizes[0] / IN_F;
  const int n_edges = in_sizes[1];
  const int nb = (n_nodes + BROWS - 1) / BROWS;      // 782 buckets

  char* ws = (char*)d_ws;
  size_t off = 0;
  auto carve = [&](size_t bytes) { void* p = ws + off; off = (off + bytes + 255) & ~(size_t)255; return p; };
  unsigned short* sup = (unsigned short*)carve((size_t)n_nodes * OUT_F * sizeof(unsigned short)); // 12.8 MB
  short* wt           = (short*)carve((size_t)IN_F * OUT_F * sizeof(short));                      // 32 KB
  int*   cursor       = (int*)  carve((size_t)nb * sizeof(int));
  int2*  slab         = (int2*) carve((size_t)nb * BCAP * sizeof(int2));                          // 12.8 MB

  prep_wt<<<(IN_F * OUT_F) / 256, 256, 0, stream>>>(w, wt);
  gemm_mfma<<<(n_nodes + 63) / 64, 256, 0, stream>>>(x, wt, sup, n_nodes);
  init_cursor<<<(nb + 255) / 256, 256, 0, stream>>>(cursor, nb);
  bin_edges<<<(n_edges + 4095) / 4096, 256, 0, stream>>>(erow, ecol, eval_, cursor, slab,
                                                         n_edges, nb);
  spmm_bucket<<<nb, 256, 0, stream>>>(cursor, slab, (const unsigned*)sup, bias, out, n_nodes);
}

// Round 6
// 152.007 us; speedup vs baseline: 5.2805x; 5.2805x over previous
//
#include <hip/hip_runtime.h>

#define IN_F 128
#define OUT_F 128
#define BROWS 64        // destination rows per bucket
#define BCAP  2048      // slab capacity per bucket; E[edges/bucket]=1024 -> P(overflow)~0
#define NBMAX 1024      // LDS histogram size (>= n_buckets = 782)

typedef __attribute__((ext_vector_type(8))) short short8;   // 8 bf16 = 4 VGPRs
typedef __attribute__((ext_vector_type(4))) float floatx4;  // MFMA C/D

// fp32 -> bf16 (RNE) as raw short
__device__ __forceinline__ short f2bf(float f) {
  union { float f; unsigned u; } v; v.f = f;
  unsigned u = v.u;
  unsigned r = (u + 0x7fffu + ((u >> 16) & 1u)) >> 16;
  return (short)r;
}
__device__ __forceinline__ float bflo(unsigned u) { return __uint_as_float(u << 16); }
__device__ __forceinline__ float bfhi(unsigned u) { return __uint_as_float(u & 0xffff0000u); }

// ---------------------------------------------------------------------------
// Prep: wt[n][k] = bf16(W[k][n])
// ---------------------------------------------------------------------------
__global__ __launch_bounds__(256) void prep_wt(const float* __restrict__ w,
                                               short* __restrict__ wt) {
  int i = blockIdx.x * 256 + threadIdx.x;   // i = n*128 + k
  int n = i >> 7, k = i & 127;
  wt[i] = f2bf(w[k * 128 + n]);
}

// ---------------------------------------------------------------------------
// GEMM: sup(bf16) = X(fp32->bf16) @ W via mfma_f32_16x16x32_bf16. (unchanged)
// ---------------------------------------------------------------------------
__global__ __launch_bounds__(256) void gemm_mfma(const float* __restrict__ x,
                                                 const short* __restrict__ wt,
                                                 unsigned short* __restrict__ sup,
                                                 int n) {
  const int w    = threadIdx.x >> 6;
  const int lane = threadIdx.x & 63;
  const int m    = lane & 15;
  const int q    = lane >> 4;
  const int row  = blockIdx.x * 64 + w * 16 + m;

  floatx4 acc[8];
#pragma unroll
  for (int t = 0; t < 8; ++t) acc[t] = (floatx4)(0.f);

#pragma unroll
  for (int kk = 0; kk < 4; ++kk) {
    short8 a;
    if (row < n) {
      const float4* px = (const float4*)(x + (size_t)row * IN_F + kk * 32 + q * 8);
      float4 lo = px[0], hi = px[1];
      a[0] = f2bf(lo.x); a[1] = f2bf(lo.y); a[2] = f2bf(lo.z); a[3] = f2bf(lo.w);
      a[4] = f2bf(hi.x); a[5] = f2bf(hi.y); a[6] = f2bf(hi.z); a[7] = f2bf(hi.w);
    } else {
      a = (short8)(0);
    }
#pragma unroll
    for (int t = 0; t < 8; ++t) {
      short8 b = *(const short8*)(wt + (size_t)(16 * t + m) * 128 + kk * 32 + q * 8);
      acc[t] = __builtin_amdgcn_mfma_f32_16x16x32_bf16(a, b, acc[t], 0, 0, 0);
    }
  }

#pragma unroll
  for (int r = 0; r < 4; ++r) {
    int row_out = blockIdx.x * 64 + w * 16 + q * 4 + r;
    if (row_out < n) {
#pragma unroll
      for (int t = 0; t < 8; ++t) {
        sup[(size_t)row_out * OUT_F + 16 * t + m] = (unsigned short)f2bf(acc[t][r]);
      }
    }
  }
}

// ---------------------------------------------------------------------------
// cursor[b] = b * BCAP
// ---------------------------------------------------------------------------
__global__ __launch_bounds__(256) void init_cursor(int* __restrict__ cursor, int nb) {
  int b = blockIdx.x * 256 + threadIdx.x;
  if (b < nb) cursor[b] = b * BCAP;
}

// ---------------------------------------------------------------------------
// Bin edges into 64-row buckets (unchanged from round 5: grouped writes,
// one global atomic per (block,bucket)). Record: col | (row_local<<16), val.
// ---------------------------------------------------------------------------
__global__ __launch_bounds__(256) void bin_edges(const int* __restrict__ erow,
                                                 const int* __restrict__ ecol,
                                                 const float* __restrict__ eval_,
                                                 int* __restrict__ cursor,
                                                 int2* __restrict__ slab,
                                                 int n_edges, int nb) {
  __shared__ int lhist[NBMAX];
  const int t = threadIdx.x;
  for (int b = t; b < nb; b += 256) lhist[b] = 0;
  __syncthreads();

  const int base = blockIdx.x * 4096;
  int meta[16], col[16]; float val[16];
#pragma unroll
  for (int i = 0; i < 16; ++i) {
    int e = base + i * 256 + t;
    meta[i] = -1;
    if (e < n_edges) {
      int r  = erow[e];
      col[i] = ecol[e];
      val[i] = eval_[e];
      int b = r >> 6, rl = r & 63;
      int rank = atomicAdd(&lhist[b], 1);            // rank within (block,bucket)
      meta[i] = (b << 18) | (rl << 12) | rank;       // 10b | 6b | 12b
    }
  }
  __syncthreads();

  for (int b = t; b < nb; b += 256) {
    int c = lhist[b];
    lhist[b] = c ? atomicAdd(&cursor[b], c) : 0;     // reserve; overwrite with base
  }
  __syncthreads();

#pragma unroll
  for (int i = 0; i < 16; ++i) {
    if (meta[i] >= 0) {
      int b = meta[i] >> 18, rl = (meta[i] >> 12) & 63, rank = meta[i] & 0xfff;
      int pos = lhist[b] + rank;
      if (pos < (b + 1) * BCAP)                      // overflow guard (never fires)
        slab[pos] = make_int2(col[i] | (rl << 16), __float_as_int(val[i]));
    }
  }
}

// ---------------------------------------------------------------------------
// SpMM consumer: one block per bucket.
// Phase A: LDS counting-sort of the bucket's records by local row (int LDS
//          atomics only — native ds_add_u32, no fp CAS loops).
// Phase B: register gather, round-4 layout: 4 rows/wave x 16 lanes x uint4
//          (1 KB per load instr), depth-2 sup pipeline (2 KB in flight/wave).
// ---------------------------------------------------------------------------
__global__ __launch_bounds__(256) void spmm_sorted(const int* __restrict__ cursor,
                                                   const int2* __restrict__ slab,
                                                   const uint4* __restrict__ supv,
                                                   const float* __restrict__ bias,
                                                   float* __restrict__ out,
                                                   int n_nodes) {
  __shared__ int2 srec[BCAP];        // 16 KB sorted records
  __shared__ int  roff[BROWS + 1];   // row segment offsets
  __shared__ int  rcur[BROWS];       // counting cursors
  const int t = threadIdx.x, b = blockIdx.x;
  const int start = b * BCAP;
  const int cnt = min(cursor[b] - start, BCAP);
  const int w = t >> 6, lane = t & 63;

  if (t < BROWS) rcur[t] = 0;
  __syncthreads();
  // pass 1: per-row counts (streaming coalesced global read)
  for (int i = t; i < cnt; i += 256)
    atomicAdd(&rcur[(slab[start + i].x >> 16) & 63], 1);
  __syncthreads();
  // wave-0 shfl scan of the 64 bins -> exclusive offsets
  if (w == 0) {
    int inc = rcur[lane];
    #pragma unroll
    for (int d = 1; d < 64; d <<= 1) {
      int u = __shfl_up(inc, d);
      if (lane >= d) inc += u;
    }
    roff[lane + 1] = inc;
    if (lane == 0) roff[0] = 0;
  }
  __syncthreads();
  if (t < BROWS) rcur[t] = roff[t];
  __syncthreads();
  // pass 2: scatter row-sorted into LDS
  for (int i = t; i < cnt; i += 256) {
    int2 r = slab[start + i];
    int p = atomicAdd(&rcur[(r.x >> 16) & 63], 1);
    srec[p] = r;
  }
  __syncthreads();

  // Phase B: gather. 4 iterations x (4 rows per wave, 16 lanes per row).
  const int g = lane >> 4, s = lane & 15;
  const float4* bp = (const float4*)bias + s * 2;
  const float4 b0 = bp[0], b1 = bp[1];

  for (int it = 0; it < 4; ++it) {
    const int rl = w * 16 + it * 4 + g;
    const int s0 = roff[rl];
    const int c  = roff[rl + 1] - s0;
    int mx = max(c, __shfl_xor(c, 16));
    mx = max(mx, __shfl_xor(mx, 32));

    float a0 = 0.f, a1 = 0.f, a2 = 0.f, a3 = 0.f,
          a4 = 0.f, a5 = 0.f, a6 = 0.f, a7 = 0.f;

    // depth-2 pipeline prime
    int2 rec0 = make_int2(0, 0), rec1 = make_int2(0, 0);
    if (0 < c) rec0 = srec[s0];
    if (1 < c) rec1 = srec[s0 + 1];
    uint4 sv0 = supv[(size_t)(rec0.x & 0xffff) * 16 + s];
    uint4 sv1 = supv[(size_t)(rec1.x & 0xffff) * 16 + s];

    for (int j = 0; j < mx; ++j) {
      int2 rec2 = make_int2(0, 0);
      if (j + 2 < c) rec2 = srec[s0 + j + 2];
      uint4 sv2 = supv[(size_t)(rec2.x & 0xffff) * 16 + s];   // issue load j+2
      float v = (j < c) ? __int_as_float(rec0.y) : 0.f;
      a0 = fmaf(v, bflo(sv0.x), a0);
      a1 = fmaf(v, bfhi(sv0.x), a1);
      a2 = fmaf(v, bflo(sv0.y), a2);
      a3 = fmaf(v, bfhi(sv0.y), a3);
      a4 = fmaf(v, bflo(sv0.z), a4);
      a5 = fmaf(v, bfhi(sv0.z), a5);
      a6 = fmaf(v, bflo(sv0.w), a6);
      a7 = fmaf(v, bfhi(sv0.w), a7);
      rec0 = rec1; rec1 = rec2; sv0 = sv1; sv1 = sv2;
    }

    const int row = b * BROWS + rl;
    if (row < n_nodes) {
      float4* op = (float4*)(out + (size_t)row * OUT_F + s * 8);
      op[0] = make_float4(a0 + b0.x, a1 + b0.y, a2 + b0.z, a3 + b0.w);
      op[1] = make_float4(a4 + b1.x, a5 + b1.y, a6 + b1.z, a7 + b1.w);
    }
  }
}

extern "C" void kernel_launch(void* const* d_in, const int* in_sizes, int n_in,
                              void* d_out, int out_size, void* d_ws, size_t ws_size,
                              hipStream_t stream) {
  const float* x     = (const float*)d_in[0];
  const int*   erow  = (const int*)d_in[1];
  const int*   ecol  = (const int*)d_in[2];
  const float* eval_ = (const float*)d_in[3];
  const float* w     = (const float*)d_in[4];
  const float* bias  = (const float*)d_in[5];
  float* out = (float*)d_out;

  const int n_nodes = in_sizes[0] / IN_F;
  const int n_edges = in_sizes[1];
  const int nb = (n_nodes + BROWS - 1) / BROWS;      // 782 buckets

  char* ws = (char*)d_ws;
  size_t off = 0;
  auto carve = [&](size_t bytes) { void* p = ws + off; off = (off + bytes + 255) & ~(size_t)255; return p; };
  unsigned short* sup = (unsigned short*)carve((size_t)n_nodes * OUT_F * sizeof(unsigned short)); // 12.8 MB
  short* wt           = (short*)carve((size_t)IN_F * OUT_F * sizeof(short));                      // 32 KB
  int*   cursor       = (int*)  carve((size_t)nb * sizeof(int));
  int2*  slab         = (int2*) carve((size_t)nb * BCAP * sizeof(int2));                          // 12.8 MB

  prep_wt<<<(IN_F * OUT_F) / 256, 256, 0, stream>>>(w, wt);
  gemm_mfma<<<(n_nodes + 63) / 64, 256, 0, stream>>>(x, wt, sup, n_nodes);
  init_cursor<<<(nb + 255) / 256, 256, 0, stream>>>(cursor, nb);
  bin_edges<<<(n_edges + 4095) / 4096, 256, 0, stream>>>(erow, ecol, eval_, cursor, slab,
                                                         n_edges, nb);
  spmm_sorted<<<nb, 256, 0, stream>>>(cursor, slab, (const uint4*)sup, bias, out, n_nodes);
}

// Round 7
// 149.669 us; speedup vs baseline: 5.3630x; 1.0156x over previous
//
#include <hip/hip_runtime.h>

#define IN_F 128
#define OUT_F 128
#define BROWS 64        // destination rows per bucket
#define BCAP  2048      // slab capacity per bucket; E[edges/bucket]=1024 -> P(overflow)~0
#define NBMAX 1024      // LDS histogram size (>= n_buckets = 782)

typedef __attribute__((ext_vector_type(8))) short short8;   // 8 bf16 = 4 VGPRs
typedef __attribute__((ext_vector_type(4))) float floatx4;  // MFMA C/D

// fp32 -> bf16 (RNE) as raw short
__device__ __forceinline__ short f2bf(float f) {
  union { float f; unsigned u; } v; v.f = f;
  unsigned u = v.u;
  unsigned r = (u + 0x7fffu + ((u >> 16) & 1u)) >> 16;
  return (short)r;
}
__device__ __forceinline__ float bflo(unsigned u) { return __uint_as_float(u << 16); }
__device__ __forceinline__ float bfhi(unsigned u) { return __uint_as_float(u & 0xffff0000u); }

// ---------------------------------------------------------------------------
// Prep (fused): wt[n][k] = bf16(W[k][n]) AND cursor[b] = b*BCAP.
// grid 64 x 256 = 16384 threads covers both ranges.
// ---------------------------------------------------------------------------
__global__ __launch_bounds__(256) void prep_all(const float* __restrict__ w,
                                                short* __restrict__ wt,
                                                int* __restrict__ cursor, int nb) {
  int i = blockIdx.x * 256 + threadIdx.x;   // i = n*128 + k
  int n = i >> 7, k = i & 127;
  wt[i] = f2bf(w[k * 128 + n]);
  if (i < nb) cursor[i] = i * BCAP;
}

// ---------------------------------------------------------------------------
// GEMM: sup(bf16) = X(fp32->bf16) @ W via mfma_f32_16x16x32_bf16.
// Epilogue: stage each wave's 16x128 bf16 tile in LDS (stride 136 shorts ->
// worst 2-way bank aliasing = free), then 256B-contiguous uint4 stores.
// ---------------------------------------------------------------------------
__global__ __launch_bounds__(256) void gemm_mfma(const float* __restrict__ x,
                                                 const short* __restrict__ wt,
                                                 unsigned short* __restrict__ sup,
                                                 int n) {
  __shared__ __align__(16) unsigned short stile[4][16 * 136];  // 17 KB
  const int w    = threadIdx.x >> 6;
  const int lane = threadIdx.x & 63;
  const int m    = lane & 15;
  const int q    = lane >> 4;
  const int row  = blockIdx.x * 64 + w * 16 + m;

  floatx4 acc[8];
#pragma unroll
  for (int t = 0; t < 8; ++t) acc[t] = (floatx4)(0.f);

#pragma unroll
  for (int kk = 0; kk < 4; ++kk) {
    short8 a;
    if (row < n) {
      const float4* px = (const float4*)(x + (size_t)row * IN_F + kk * 32 + q * 8);
      float4 lo = px[0], hi = px[1];
      a[0] = f2bf(lo.x); a[1] = f2bf(lo.y); a[2] = f2bf(lo.z); a[3] = f2bf(lo.w);
      a[4] = f2bf(hi.x); a[5] = f2bf(hi.y); a[6] = f2bf(hi.z); a[7] = f2bf(hi.w);
    } else {
      a = (short8)(0);
    }
#pragma unroll
    for (int t = 0; t < 8; ++t) {
      short8 b = *(const short8*)(wt + (size_t)(16 * t + m) * 128 + kk * 32 + q * 8);
      acc[t] = __builtin_amdgcn_mfma_f32_16x16x32_bf16(a, b, acc[t], 0, 0, 0);
    }
  }

  // stage C tile: lane holds (row_l = q*4+r, col = 16t+m)
#pragma unroll
  for (int r = 0; r < 4; ++r)
#pragma unroll
    for (int t = 0; t < 8; ++t)
      stile[w][(q * 4 + r) * 136 + 16 * t + m] = (unsigned short)f2bf(acc[t][r]);

  // re-read + coalesced store (same-wave LDS dependency; no __syncthreads)
#pragma unroll
  for (int p = 0; p < 4; ++p) {
    int row_l = p * 4 + (lane >> 4);
    int row_g = blockIdx.x * 64 + w * 16 + row_l;
    if (row_g < n) {
      uint4 v = *(const uint4*)&stile[w][row_l * 136 + (lane & 15) * 8];
      *(uint4*)(sup + (size_t)row_g * OUT_F + (lane & 15) * 8) = v;
    }
  }
}

// ---------------------------------------------------------------------------
// Bin edges into 64-row buckets (grouped writes, one global atomic per
// (block,bucket)). Record: col | (row_local<<16), val.
// ---------------------------------------------------------------------------
__global__ __launch_bounds__(256) void bin_edges(const int* __restrict__ erow,
                                                 const int* __restrict__ ecol,
                                                 const float* __restrict__ eval_,
                                                 int* __restrict__ cursor,
                                                 int2* __restrict__ slab,
                                                 int n_edges, int nb) {
  __shared__ int lhist[NBMAX];
  const int t = threadIdx.x;
  for (int b = t; b < nb; b += 256) lhist[b] = 0;
  __syncthreads();

  const int base = blockIdx.x * 4096;
  int meta[16], col[16]; float val[16];
#pragma unroll
  for (int i = 0; i < 16; ++i) {
    int e = base + i * 256 + t;
    meta[i] = -1;
    if (e < n_edges) {
      int r  = erow[e];
      col[i] = ecol[e];
      val[i] = eval_[e];
      int b = r >> 6, rl = r & 63;
      int rank = atomicAdd(&lhist[b], 1);            // rank within (block,bucket)
      meta[i] = (b << 18) | (rl << 12) | rank;       // 10b | 6b | 12b
    }
  }
  __syncthreads();

  for (int b = t; b < nb; b += 256) {
    int c = lhist[b];
    lhist[b] = c ? atomicAdd(&cursor[b], c) : 0;     // reserve; overwrite with base
  }
  __syncthreads();

#pragma unroll
  for (int i = 0; i < 16; ++i) {
    if (meta[i] >= 0) {
      int b = meta[i] >> 18, rl = (meta[i] >> 12) & 63, rank = meta[i] & 0xfff;
      int pos = lhist[b] + rank;
      if (pos < (b + 1) * BCAP)                      // overflow guard (never fires)
        slab[pos] = make_int2(col[i] | (rl << 16), __float_as_int(val[i]));
    }
  }
}

// ---------------------------------------------------------------------------
// SpMM consumer: one block per bucket.
// Phase A: LDS counting-sort by local row (int LDS atomics only) + wave-0
//          bitonic sort of the 64 rows by edge count -> load-balanced groups
//          (4 count-adjacent rows per wave-group => max ~ mean).
// Phase B: register gather: 4 rows/wave x 16 lanes x uint4 (1 KB per load
//          instr), depth-2 sup pipeline.
// ---------------------------------------------------------------------------
__global__ __launch_bounds__(256) void spmm_sorted(const int* __restrict__ cursor,
                                                   const int2* __restrict__ slab,
                                                   const uint4* __restrict__ supv,
                                                   const float* __restrict__ bias,
                                                   float* __restrict__ out,
                                                   int n_nodes) {
  __shared__ int2 srec[BCAP];        // 16 KB sorted records
  __shared__ int  roff[BROWS + 1];   // row segment offsets
  __shared__ int  rcur[BROWS];       // counting cursors
  __shared__ int  srow[BROWS];       // rows ordered by ascending count
  const int t = threadIdx.x, b = blockIdx.x;
  const int start = b * BCAP;
  const int cnt = min(cursor[b] - start, BCAP);
  const int w = t >> 6, lane = t & 63;

  if (t < BROWS) rcur[t] = 0;
  __syncthreads();
  // pass 1: per-row counts (streaming coalesced global read)
  for (int i = t; i < cnt; i += 256)
    atomicAdd(&rcur[(slab[start + i].x >> 16) & 63], 1);
  __syncthreads();
  // wave 0: shfl scan of 64 bins -> exclusive offsets, then bitonic sort of
  // rows by count (key = (cnt<<6)|lane, unique) for balanced gather groups.
  if (w == 0) {
    int c = rcur[lane];
    int inc = c;
#pragma unroll
    for (int d = 1; d < 64; d <<= 1) {
      int u = __shfl_up(inc, d);
      if (lane >= d) inc += u;
    }
    roff[lane + 1] = inc;
    if (lane == 0) roff[0] = 0;
    int key = (c << 6) | lane;
#pragma unroll
    for (int k = 2; k <= 64; k <<= 1) {
#pragma unroll
      for (int j = k >> 1; j > 0; j >>= 1) {
        int other = __shfl_xor(key, j);
        bool keep_min = (((lane & k) == 0) == ((lane & j) == 0));
        int mn = min(key, other), mx = max(key, other);
        key = keep_min ? mn : mx;
      }
    }
    srow[lane] = key & 63;
  }
  __syncthreads();
  if (t < BROWS) rcur[t] = roff[t];
  __syncthreads();
  // pass 2: scatter row-sorted into LDS (slab segment is L2-hot from pass 1)
  for (int i = t; i < cnt; i += 256) {
    int2 r = slab[start + i];
    int p = atomicAdd(&rcur[(r.x >> 16) & 63], 1);
    srec[p] = r;
  }
  __syncthreads();

  // Phase B: gather. 4 iterations x (4 rows per wave, 16 lanes per row).
  const int g = lane >> 4, s = lane & 15;
  const float4* bp = (const float4*)bias + s * 2;
  const float4 b0 = bp[0], b1 = bp[1];

  for (int it = 0; it < 4; ++it) {
    const int rl = srow[it * 16 + w * 4 + g];        // count-adjacent group
    const int s0 = roff[rl];
    const int c  = roff[rl + 1] - s0;
    int mx = max(c, __shfl_xor(c, 16));
    mx = max(mx, __shfl_xor(mx, 32));

    float a0 = 0.f, a1 = 0.f, a2 = 0.f, a3 = 0.f,
          a4 = 0.f, a5 = 0.f, a6 = 0.f, a7 = 0.f;

    // depth-2 pipeline prime
    int2 rec0 = make_int2(0, 0), rec1 = make_int2(0, 0);
    if (0 < c) rec0 = srec[s0];
    if (1 < c) rec1 = srec[s0 + 1];
    uint4 sv0 = supv[(size_t)(rec0.x & 0xffff) * 16 + s];
    uint4 sv1 = supv[(size_t)(rec1.x & 0xffff) * 16 + s];

    for (int j = 0; j < mx; ++j) {
      int2 rec2 = make_int2(0, 0);
      if (j + 2 < c) rec2 = srec[s0 + j + 2];
      uint4 sv2 = supv[(size_t)(rec2.x & 0xffff) * 16 + s];   // issue load j+2
      float v = (j < c) ? __int_as_float(rec0.y) : 0.f;
      a0 = fmaf(v, bflo(sv0.x), a0);
      a1 = fmaf(v, bfhi(sv0.x), a1);
      a2 = fmaf(v, bflo(sv0.y), a2);
      a3 = fmaf(v, bfhi(sv0.y), a3);
      a4 = fmaf(v, bflo(sv0.z), a4);
      a5 = fmaf(v, bfhi(sv0.z), a5);
      a6 = fmaf(v, bflo(sv0.w), a6);
      a7 = fmaf(v, bfhi(sv0.w), a7);
      rec0 = rec1; rec1 = rec2; sv0 = sv1; sv1 = sv2;
    }

    const int row = b * BROWS + rl;
    if (row < n_nodes) {
      float4* op = (float4*)(out + (size_t)row * OUT_F + s * 8);
      op[0] = make_float4(a0 + b0.x, a1 + b0.y, a2 + b0.z, a3 + b0.w);
      op[1] = make_float4(a4 + b1.x, a5 + b1.y, a6 + b1.z, a7 + b1.w);
    }
  }
}

extern "C" void kernel_launch(void* const* d_in, const int* in_sizes, int n_in,
                              void* d_out, int out_size, void* d_ws, size_t ws_size,
                              hipStream_t stream) {
  const float* x     = (const float*)d_in[0];
  const int*   erow  = (const int*)d_in[1];
  const int*   ecol  = (const int*)d_in[2];
  const float* eval_ = (const float*)d_in[3];
  const float* w     = (const float*)d_in[4];
  const float* bias  = (const float*)d_in[5];
  float* out = (float*)d_out;

  const int n_nodes = in_sizes[0] / IN_F;
  const int n_edges = in_sizes[1];
  const int nb = (n_nodes + BROWS - 1) / BROWS;      // 782 buckets

  char* ws = (char*)d_ws;
  size_t off = 0;
  auto carve = [&](size_t bytes) { void* p = ws + off; off = (off + bytes + 255) & ~(size_t)255; return p; };
  unsigned short* sup = (unsigned short*)carve((size_t)n_nodes * OUT_F * sizeof(unsigned short)); // 12.8 MB
  short* wt           = (short*)carve((size_t)IN_F * OUT_F * sizeof(short));                      // 32 KB
  int*   cursor       = (int*)  carve((size_t)nb * sizeof(int));
  int2*  slab         = (int2*) carve((size_t)nb * BCAP * sizeof(int2));                          // 12.8 MB

  prep_all<<<64, 256, 0, stream>>>(w, wt, cursor, nb);
  gemm_mfma<<<(n_nodes + 63) / 64, 256, 0, stream>>>(x, wt, sup, n_nodes);
  bin_edges<<<(n_edges + 4095) / 4096, 256, 0, stream>>>(erow, ecol, eval_, cursor, slab,
                                                         n_edges, nb);
  spmm_sorted<<<nb, 256, 0, stream>>>(cursor, slab, (const uint4*)sup, bias, out, n_nodes);
}